// Round 1
// baseline (3852.747 us; speedup 1.0000x reference)
//
#include <hip/hip_runtime.h>
#include <math.h>

namespace {

constexpr int kH = 500, kW = 500, kNV = 5023, kNF = 9976, kB = 2;
constexpr float kFocal = 1015.0f;
constexpr float kEps = 1e-6f;
constexpr int kChunk = 512;   // faces staged in LDS per iteration (32 KiB)

__global__ void zero_k(float* p, int n) {
  int i = blockIdx.x * 256 + threadIdx.x;
  if (i < n) p[i] = 0.0f;
}

__device__ inline void cross3(float ax, float ay, float az,
                              float bx, float by, float bz,
                              float& cx, float& cy, float& cz) {
  cx = ay * bz - az * by;
  cy = az * bx - ax * bz;
  cz = ax * by - ay * bx;
}

// One thread per (batch, face): scatter-add the three cross products into the
// per-vertex normal accumulator. Order of float atomics is nondeterministic but
// normals only feed continuous shading (error << 2e-2 threshold).
__global__ void normal_accum_k(const float* __restrict__ verts,
                               const int* __restrict__ faces,
                               float* __restrict__ nacc) {
  int idx = blockIdx.x * 256 + threadIdx.x;
  if (idx >= kB * kNF) return;
  int b = idx / kNF, f = idx - b * kNF;
  int i0 = faces[3 * f + 0], i1 = faces[3 * f + 1], i2 = faces[3 * f + 2];
  const float* vb = verts + (size_t)b * kNV * 3;
  float x0 = vb[3 * i0], y0 = vb[3 * i0 + 1], z0 = vb[3 * i0 + 2];
  float x1 = vb[3 * i1], y1 = vb[3 * i1 + 1], z1 = vb[3 * i1 + 2];
  float x2 = vb[3 * i2], y2 = vb[3 * i2 + 1], z2 = vb[3 * i2 + 2];
  float* nb = nacc + (size_t)b * kNV * 3;
  float cx, cy, cz;
  // n[faces[:,1]] += cross(v2-v1, v0-v1)
  cross3(x2 - x1, y2 - y1, z2 - z1, x0 - x1, y0 - y1, z0 - z1, cx, cy, cz);
  atomicAdd(nb + 3 * i1 + 0, cx);
  atomicAdd(nb + 3 * i1 + 1, cy);
  atomicAdd(nb + 3 * i1 + 2, cz);
  // n[faces[:,2]] += cross(v0-v2, v1-v2)
  cross3(x0 - x2, y0 - y2, z0 - z2, x1 - x2, y1 - y2, z1 - z2, cx, cy, cz);
  atomicAdd(nb + 3 * i2 + 0, cx);
  atomicAdd(nb + 3 * i2 + 1, cy);
  atomicAdd(nb + 3 * i2 + 2, cz);
  // n[faces[:,0]] += cross(v1-v0, v2-v0)
  cross3(x1 - x0, y1 - y0, z1 - z0, x2 - x0, y2 - y0, z2 - z0, cx, cy, cz);
  atomicAdd(nb + 3 * i0 + 0, cx);
  atomicAdd(nb + 3 * i0 + 1, cy);
  atomicAdd(nb + 3 * i0 + 2, cz);
}

// One thread per (batch, vertex): normalize accumulated normal (in place) and
// compute the projected screen coords. Projection feeds discrete raster
// decisions -> use _rn intrinsics to forbid FMA contraction (mirror numpy).
__global__ void proj_norm_k(const float* __restrict__ verts,
                            float* __restrict__ nacc,
                            float4* __restrict__ proj) {
  int idx = blockIdx.x * 256 + threadIdx.x;
  if (idx >= kB * kNV) return;
  float nx = nacc[3 * idx + 0], ny = nacc[3 * idx + 1], nz = nacc[3 * idx + 2];
  float nn = sqrtf(nx * nx + ny * ny + nz * nz);
  float nd = fmaxf(nn, kEps);
  nacc[3 * idx + 0] = nx / nd;
  nacc[3 * idx + 1] = ny / nd;
  nacc[3 * idx + 2] = nz / nd;
  float vx = verts[3 * idx + 0], vy = verts[3 * idx + 1], vz = verts[3 * idx + 2];
  // verts_c = verts_w * [-1, 1, -1]
  float xc = -vx, yc = vy, zc = -vz;
  float zs = fmaxf(zc, kEps);
  float px = __fsub_rn(0.5f * kW, __fdiv_rn(__fmul_rn(kFocal, xc), zs));
  float py = __fsub_rn(0.5f * kH, __fdiv_rn(__fmul_rn(kFocal, yc), zs));
  proj[idx] = make_float4(px, py, zc, 0.0f);
}

// Per-face raster constants, 4x float4 per face:
//   [0] bbox {minx, maxx, miny, maxy}  (+inf/-inf sentinel if invalid)
//   [1] {cx, cy, A0=by-cy, B0=cx-bx}
//   [2] {A1=cy-ay, B1=ax-cx, denom, za}
//   [3] {zb, zc, 0, 0}
__global__ void face_setup_k(const float4* __restrict__ proj,
                             const int* __restrict__ faces,
                             float4* __restrict__ fd) {
  int idx = blockIdx.x * 256 + threadIdx.x;
  if (idx >= kB * kNF) return;
  int b = idx / kNF, f = idx - b * kNF;
  int i0 = faces[3 * f + 0], i1 = faces[3 * f + 1], i2 = faces[3 * f + 2];
  float4 A = proj[b * kNV + i0];
  float4 Bv = proj[b * kNV + i1];
  float4 C = proj[b * kNV + i2];
  float ax = A.x, ay = A.y, za = A.z;
  float bx = Bv.x, by = Bv.y, zb = Bv.z;
  float cx = C.x, cy = C.y, zc = C.z;
  float A0 = __fsub_rn(by, cy);
  float B0 = __fsub_rn(cx, bx);
  float A1 = __fsub_rn(cy, ay);
  float B1 = __fsub_rn(ax, cx);   // == (ax - cx), also reused in denom
  float e = __fsub_rn(ay, cy);
  float den = __fadd_rn(__fmul_rn(A0, B1), __fmul_rn(B0, e));
  bool valid = (fabsf(den) >= kEps) && (za > kEps) && (zb > kEps) && (zc > kEps);
  float ds = valid ? den : 1.0f;
  float mnx, mxx, mny, mxy;
  if (valid) {
    // Conservative 0.5px margin; rounded inside-tests deviate from the exact
    // triangle by ~1e-4 px at most, so bbox rejection is safe.
    mnx = fminf(fminf(ax, bx), cx) - 0.5f;
    mxx = fmaxf(fmaxf(ax, bx), cx) + 0.5f;
    mny = fminf(fminf(ay, by), cy) - 0.5f;
    mxy = fmaxf(fmaxf(ay, by), cy) + 0.5f;
  } else {
    mnx = INFINITY; mxx = -INFINITY; mny = INFINITY; mxy = -INFINITY;
  }
  float4* o = fd + (size_t)idx * 4;
  o[0] = make_float4(mnx, mxx, mny, mxy);
  o[1] = make_float4(cx, cy, A0, B0);
  o[2] = make_float4(A1, B1, ds, za);
  o[3] = make_float4(zb, zc, 0.0f, 0.0f);
}

// 16x16-pixel tile per 256-thread block; faces streamed through LDS in chunks.
// Discrete decisions (inside tests, depth argmin) replicate the reference's
// float32 rounding exactly; strict '<' keeps the first (lowest-index) minimum,
// matching jnp.argmin tie-breaking.
__global__ __launch_bounds__(256) void raster_k(const float4* __restrict__ fd,
                                                const float* __restrict__ verts,
                                                const float* __restrict__ nrm,
                                                const int* __restrict__ faces,
                                                float* __restrict__ out) {
  __shared__ float4 sh[kChunk * 4];
  int b = blockIdx.z;
  int tx = threadIdx.x & 15, ty = threadIdx.x >> 4;
  int x = blockIdx.x * 16 + tx;
  int y = blockIdx.y * 16 + ty;
  float xp = (float)x + 0.5f;
  float yp = (float)y + 0.5f;

  float zmin = INFINITY;
  int best = 0;
  float bw0 = 0.0f, bw1 = 0.0f, bw2 = 0.0f;

  const float4* fb = fd + (size_t)b * kNF * 4;
  for (int base = 0; base < kNF; base += kChunk) {
    int n = min(kChunk, kNF - base);
    __syncthreads();
    for (int j = threadIdx.x; j < n * 4; j += 256) sh[j] = fb[base * 4 + j];
    __syncthreads();
    for (int j = 0; j < n; ++j) {
      float4 bb = sh[j * 4 + 0];
      if (xp < bb.x || xp > bb.y || yp < bb.z || yp > bb.w) continue;
      float4 c0 = sh[j * 4 + 1];
      float4 c1 = sh[j * 4 + 2];
      float dx = __fsub_rn(xp, c0.x);
      float dy = __fsub_rn(yp, c0.y);
      float num0 = __fadd_rn(__fmul_rn(c0.z, dx), __fmul_rn(c0.w, dy));
      float num1 = __fadd_rn(__fmul_rn(c1.x, dx), __fmul_rn(c1.y, dy));
      float den = c1.z;
      // Fast conservative sign reject (exact w>=0 re-check after division).
      if (num0 * den < 0.0f || num1 * den < 0.0f) continue;
      float w0 = __fdiv_rn(num0, den);
      float w1 = __fdiv_rn(num1, den);
      float w2 = __fsub_rn(__fsub_rn(1.0f, w0), w1);
      if (!(w0 >= 0.0f) || !(w1 >= 0.0f) || !(w2 >= 0.0f)) continue;
      float4 c2 = sh[j * 4 + 3];
      float z = __fadd_rn(__fadd_rn(__fmul_rn(w0, c1.w), __fmul_rn(w1, c2.x)),
                          __fmul_rn(w2, c2.y));
      if (z < zmin) {
        zmin = z; best = base + j; bw0 = w0; bw1 = w1; bw2 = w2;
      }
    }
  }

  if (x >= kW || y >= kH) return;

  float r, a;
  if (zmin < INFINITY) {
    int i0 = faces[3 * best + 0], i1 = faces[3 * best + 1], i2 = faces[3 * best + 2];
    const float* vb = verts + (size_t)b * kNV * 3;
    const float* nb = nrm + (size_t)b * kNV * 3;
    float px_ = bw0 * vb[3 * i0 + 0] + bw1 * vb[3 * i1 + 0] + bw2 * vb[3 * i2 + 0];
    float py_ = bw0 * vb[3 * i0 + 1] + bw1 * vb[3 * i1 + 1] + bw2 * vb[3 * i2 + 1];
    float pz_ = bw0 * vb[3 * i0 + 2] + bw1 * vb[3 * i1 + 2] + bw2 * vb[3 * i2 + 2];
    float nx = bw0 * nb[3 * i0 + 0] + bw1 * nb[3 * i1 + 0] + bw2 * nb[3 * i2 + 0];
    float ny = bw0 * nb[3 * i0 + 1] + bw1 * nb[3 * i1 + 1] + bw2 * nb[3 * i2 + 1];
    float nz = bw0 * nb[3 * i0 + 2] + bw1 * nb[3 * i1 + 2] + bw2 * nb[3 * i2 + 2];
    float nn = sqrtf(nx * nx + ny * ny + nz * nz);
    float nd = fmaxf(nn, kEps);
    nx /= nd; ny /= nd; nz /= nd;
    float pn = sqrtf(px_ * px_ + py_ * py_ + pz_ * pz_);
    float pd = fmaxf(pn, kEps);
    float lx = -px_ / pd, ly = -py_ / pd, lz = -pz_ / pd;
    float s = nx * lx + ny * ly + nz * lz;
    float ndl = fmaxf(s, 0.0f);
    float rx = 2.0f * s * nx - lx;
    float ry = 2.0f * s * ny - ly;
    float rz = 2.0f * s * nz - lz;
    float vdr = fmaxf(lx * rx + ly * ry + lz * rz, 0.0f);
    float q = vdr;               // vdr^64 via 6 squarings
    q = q * q; q = q * q; q = q * q; q = q * q; q = q * q; q = q * q;
    float shade = 0.5f * (0.5f + 0.3f * ndl) + 0.2f * q;
    r = fminf(fmaxf(shade, 0.0f), 255.0f);
    a = 1.0f;
  } else {
    r = 1.0f;   // background rgb = 1.0
    a = 0.0f;   // mask = 0
  }
  float4* op = (float4*)out;
  op[((size_t)b * kH + y) * kW + x] = make_float4(r, r, r, a);
}

}  // namespace

extern "C" void kernel_launch(void* const* d_in, const int* in_sizes, int n_in,
                              void* d_out, int out_size, void* d_ws, size_t ws_size,
                              hipStream_t stream) {
  (void)in_sizes; (void)n_in; (void)out_size; (void)ws_size;
  const float* verts = (const float*)d_in[0];   // (B, NV, 3) f32
  const int* faces = (const int*)d_in[1];       // (NF, 3) i32
  float* out = (float*)d_out;                   // (B, H, W, 4) f32
  float* ws = (float*)d_ws;

  // ws layout (floats): [0, 30138) normal accum/normals; [30144, 70328) proj
  // float4s; [70328, ...) face data (B*NF*4 float4 = 1.22 MiB). Total ~1.5 MiB.
  float* nacc = ws;
  float4* proj = (float4*)(ws + 30144);
  float4* fd = (float4*)(ws + 70328);

  int nTot = kB * kNV * 3;
  hipLaunchKernelGGL(zero_k, dim3((nTot + 255) / 256), dim3(256), 0, stream,
                     nacc, nTot);
  hipLaunchKernelGGL(normal_accum_k, dim3((kB * kNF + 255) / 256), dim3(256), 0,
                     stream, verts, faces, nacc);
  hipLaunchKernelGGL(proj_norm_k, dim3((kB * kNV + 255) / 256), dim3(256), 0,
                     stream, verts, nacc, proj);
  hipLaunchKernelGGL(face_setup_k, dim3((kB * kNF + 255) / 256), dim3(256), 0,
                     stream, proj, faces, fd);
  hipLaunchKernelGGL(raster_k, dim3(32, 32, kB), dim3(256), 0, stream,
                     fd, verts, nacc, faces, out);
}

// Round 2
// 2104.099 us; speedup vs baseline: 1.8311x; 1.8311x over previous
//
#include <hip/hip_runtime.h>
#include <math.h>

namespace {

constexpr int kH = 500, kW = 500, kNV = 5023, kNF = 9976, kB = 2;
constexpr float kFocal = 1015.0f;
constexpr float kEps = 1e-6f;
constexpr int kChunk = 256;   // faces tested per chunk; LDS capacity == kChunk

__global__ void zero_k(float* p, int n) {
  int i = blockIdx.x * 256 + threadIdx.x;
  if (i < n) p[i] = 0.0f;
}

__device__ inline void cross3(float ax, float ay, float az,
                              float bx, float by, float bz,
                              float& cx, float& cy, float& cz) {
  cx = ay * bz - az * by;
  cy = az * bx - ax * bz;
  cz = ax * by - ay * bx;
}

// One thread per (batch, face): scatter-add the three cross products into the
// per-vertex normal accumulator. Order of float atomics is nondeterministic but
// normals only feed continuous shading (error << 2e-2 threshold).
__global__ void normal_accum_k(const float* __restrict__ verts,
                               const int* __restrict__ faces,
                               float* __restrict__ nacc) {
  int idx = blockIdx.x * 256 + threadIdx.x;
  if (idx >= kB * kNF) return;
  int b = idx / kNF, f = idx - b * kNF;
  int i0 = faces[3 * f + 0], i1 = faces[3 * f + 1], i2 = faces[3 * f + 2];
  const float* vb = verts + (size_t)b * kNV * 3;
  float x0 = vb[3 * i0], y0 = vb[3 * i0 + 1], z0 = vb[3 * i0 + 2];
  float x1 = vb[3 * i1], y1 = vb[3 * i1 + 1], z1 = vb[3 * i1 + 2];
  float x2 = vb[3 * i2], y2 = vb[3 * i2 + 1], z2 = vb[3 * i2 + 2];
  float* nb = nacc + (size_t)b * kNV * 3;
  float cx, cy, cz;
  // n[faces[:,1]] += cross(v2-v1, v0-v1)
  cross3(x2 - x1, y2 - y1, z2 - z1, x0 - x1, y0 - y1, z0 - z1, cx, cy, cz);
  atomicAdd(nb + 3 * i1 + 0, cx);
  atomicAdd(nb + 3 * i1 + 1, cy);
  atomicAdd(nb + 3 * i1 + 2, cz);
  // n[faces[:,2]] += cross(v0-v2, v1-v2)
  cross3(x0 - x2, y0 - y2, z0 - z2, x1 - x2, y1 - y2, z1 - z2, cx, cy, cz);
  atomicAdd(nb + 3 * i2 + 0, cx);
  atomicAdd(nb + 3 * i2 + 1, cy);
  atomicAdd(nb + 3 * i2 + 2, cz);
  // n[faces[:,0]] += cross(v1-v0, v2-v0)
  cross3(x1 - x0, y1 - y0, z1 - z0, x2 - x0, y2 - y0, z2 - z0, cx, cy, cz);
  atomicAdd(nb + 3 * i0 + 0, cx);
  atomicAdd(nb + 3 * i0 + 1, cy);
  atomicAdd(nb + 3 * i0 + 2, cz);
}

// One thread per (batch, vertex): normalize accumulated normal (in place) and
// compute the projected screen coords. Projection feeds discrete raster
// decisions -> use _rn intrinsics to forbid FMA contraction (mirror numpy).
__global__ void proj_norm_k(const float* __restrict__ verts,
                            float* __restrict__ nacc,
                            float4* __restrict__ proj) {
  int idx = blockIdx.x * 256 + threadIdx.x;
  if (idx >= kB * kNV) return;
  float nx = nacc[3 * idx + 0], ny = nacc[3 * idx + 1], nz = nacc[3 * idx + 2];
  float nn = sqrtf(nx * nx + ny * ny + nz * nz);
  float nd = fmaxf(nn, kEps);
  nacc[3 * idx + 0] = nx / nd;
  nacc[3 * idx + 1] = ny / nd;
  nacc[3 * idx + 2] = nz / nd;
  float vx = verts[3 * idx + 0], vy = verts[3 * idx + 1], vz = verts[3 * idx + 2];
  // verts_c = verts_w * [-1, 1, -1]
  float xc = -vx, yc = vy, zc = -vz;
  float zs = fmaxf(zc, kEps);
  float px = __fsub_rn(0.5f * kW, __fdiv_rn(__fmul_rn(kFocal, xc), zs));
  float py = __fsub_rn(0.5f * kH, __fdiv_rn(__fmul_rn(kFocal, yc), zs));
  proj[idx] = make_float4(px, py, zc, 0.0f);
}

// Per-face raster constants, 4x float4 per face:
//   [0] bbox {minx, maxx, miny, maxy}  (+inf/-inf sentinel if invalid)
//   [1] {cx, cy, A0=by-cy, B0=cx-bx}
//   [2] {A1=cy-ay, B1=ax-cx, denom, za}
//   [3] {zb, zc, 0, 0}   (.z gets face index stuffed in during LDS compaction)
__global__ void face_setup_k(const float4* __restrict__ proj,
                             const int* __restrict__ faces,
                             float4* __restrict__ fd) {
  int idx = blockIdx.x * 256 + threadIdx.x;
  if (idx >= kB * kNF) return;
  int b = idx / kNF, f = idx - b * kNF;
  int i0 = faces[3 * f + 0], i1 = faces[3 * f + 1], i2 = faces[3 * f + 2];
  float4 A = proj[b * kNV + i0];
  float4 Bv = proj[b * kNV + i1];
  float4 C = proj[b * kNV + i2];
  float ax = A.x, ay = A.y, za = A.z;
  float bx = Bv.x, by = Bv.y, zb = Bv.z;
  float cx = C.x, cy = C.y, zc = C.z;
  float A0 = __fsub_rn(by, cy);
  float B0 = __fsub_rn(cx, bx);
  float A1 = __fsub_rn(cy, ay);
  float B1 = __fsub_rn(ax, cx);
  float e = __fsub_rn(ay, cy);
  float den = __fadd_rn(__fmul_rn(A0, B1), __fmul_rn(B0, e));
  bool valid = (fabsf(den) >= kEps) && (za > kEps) && (zb > kEps) && (zc > kEps);
  float ds = valid ? den : 1.0f;
  float mnx, mxx, mny, mxy;
  if (valid) {
    // Conservative 0.5px margin around the exact bbox.
    mnx = fminf(fminf(ax, bx), cx) - 0.5f;
    mxx = fmaxf(fmaxf(ax, bx), cx) + 0.5f;
    mny = fminf(fminf(ay, by), cy) - 0.5f;
    mxy = fmaxf(fmaxf(ay, by), cy) + 0.5f;
  } else {
    mnx = INFINITY; mxx = -INFINITY; mny = INFINITY; mxy = -INFINITY;
  }
  float4* o = fd + (size_t)idx * 4;
  o[0] = make_float4(mnx, mxx, mny, mxy);
  o[1] = make_float4(cx, cy, A0, B0);
  o[2] = make_float4(A1, B1, ds, za);
  o[3] = make_float4(zb, zc, 0.0f, 0.0f);
}

// 16x16-pixel tile per 256-thread block. Per 256-face chunk: each thread
// tile-culls one face (bbox vs tile rect) and compacts survivors into LDS
// (capacity == chunk -> no overflow possible). Pixels then test only the
// survivors. Compaction scrambles intra-chunk order, so the depth argmin uses
// the order-independent lexicographic rule (z, faceIdx) — identical to
// jnp.argmin's first-minimum tie-break. All discrete-path arithmetic uses _rn
// intrinsics to match the reference's fp32 rounding bit-for-bit.
__global__ __launch_bounds__(256) void raster_k(const float4* __restrict__ fd,
                                                const float* __restrict__ verts,
                                                const float* __restrict__ nrm,
                                                const int* __restrict__ faces,
                                                float* __restrict__ out) {
  __shared__ float4 sh[kChunk * 4];   // 16 KiB
  __shared__ int lcnt;
  int b = blockIdx.z;
  int tx = threadIdx.x & 15, ty = threadIdx.x >> 4;
  int x = blockIdx.x * 16 + tx;
  int y = blockIdx.y * 16 + ty;
  float xp = (float)x + 0.5f;
  float yp = (float)y + 0.5f;
  // Pixel-center extents of this tile.
  float tX0 = blockIdx.x * 16 + 0.5f, tX1 = blockIdx.x * 16 + 15.5f;
  float tY0 = blockIdx.y * 16 + 0.5f, tY1 = blockIdx.y * 16 + 15.5f;

  float zmin = INFINITY;
  int best = 0;
  float bw0 = 0.0f, bw1 = 0.0f, bw2 = 0.0f;

  const float4* fb = fd + (size_t)b * kNF * 4;
  for (int base = 0; base < kNF; base += kChunk) {
    __syncthreads();                       // prev inner loop done reading sh
    if (threadIdx.x == 0) lcnt = 0;
    __syncthreads();
    int j = base + threadIdx.x;
    if (j < kNF) {
      float4 bb = fb[(size_t)j * 4 + 0];
      // Invalid faces have bb = (+inf,-inf,+inf,-inf) -> always fail.
      if (bb.x <= tX1 && bb.y >= tX0 && bb.z <= tY1 && bb.w >= tY0) {
        int pos = atomicAdd(&lcnt, 1);
        float4 t1 = fb[(size_t)j * 4 + 1];
        float4 t2 = fb[(size_t)j * 4 + 2];
        float4 t3 = fb[(size_t)j * 4 + 3];
        t3.z = __int_as_float(j);
        sh[pos * 4 + 0] = bb;
        sh[pos * 4 + 1] = t1;
        sh[pos * 4 + 2] = t2;
        sh[pos * 4 + 3] = t3;
      }
    }
    __syncthreads();
    int m = lcnt;
    for (int k = 0; k < m; ++k) {
      float4 bb = sh[k * 4 + 0];
      if (xp < bb.x || xp > bb.y || yp < bb.z || yp > bb.w) continue;
      float4 c0 = sh[k * 4 + 1];
      float4 c1 = sh[k * 4 + 2];
      float dx = __fsub_rn(xp, c0.x);
      float dy = __fsub_rn(yp, c0.y);
      float num0 = __fadd_rn(__fmul_rn(c0.z, dx), __fmul_rn(c0.w, dy));
      float num1 = __fadd_rn(__fmul_rn(c1.x, dx), __fmul_rn(c1.y, dy));
      float den = c1.z;
      // Fast conservative sign reject (exact w>=0 re-check after division).
      if (num0 * den < 0.0f || num1 * den < 0.0f) continue;
      float w0 = __fdiv_rn(num0, den);
      float w1 = __fdiv_rn(num1, den);
      float w2 = __fsub_rn(__fsub_rn(1.0f, w0), w1);
      if (!(w0 >= 0.0f) || !(w1 >= 0.0f) || !(w2 >= 0.0f)) continue;
      float4 c2 = sh[k * 4 + 3];
      float z = __fadd_rn(__fadd_rn(__fmul_rn(w0, c1.w), __fmul_rn(w1, c2.x)),
                          __fmul_rn(w2, c2.y));
      int fidx = __float_as_int(c2.z);
      if (z < zmin || (z == zmin && fidx < best)) {
        zmin = z; best = fidx; bw0 = w0; bw1 = w1; bw2 = w2;
      }
    }
  }

  if (x >= kW || y >= kH) return;

  float r, a;
  if (zmin < INFINITY) {
    int i0 = faces[3 * best + 0], i1 = faces[3 * best + 1], i2 = faces[3 * best + 2];
    const float* vb = verts + (size_t)b * kNV * 3;
    const float* nb = nrm + (size_t)b * kNV * 3;
    float px_ = bw0 * vb[3 * i0 + 0] + bw1 * vb[3 * i1 + 0] + bw2 * vb[3 * i2 + 0];
    float py_ = bw0 * vb[3 * i0 + 1] + bw1 * vb[3 * i1 + 1] + bw2 * vb[3 * i2 + 1];
    float pz_ = bw0 * vb[3 * i0 + 2] + bw1 * vb[3 * i1 + 2] + bw2 * vb[3 * i2 + 2];
    float nx = bw0 * nb[3 * i0 + 0] + bw1 * nb[3 * i1 + 0] + bw2 * nb[3 * i2 + 0];
    float ny = bw0 * nb[3 * i0 + 1] + bw1 * nb[3 * i1 + 1] + bw2 * nb[3 * i2 + 1];
    float nz = bw0 * nb[3 * i0 + 2] + bw1 * nb[3 * i1 + 2] + bw2 * nb[3 * i2 + 2];
    float nn = sqrtf(nx * nx + ny * ny + nz * nz);
    float nd = fmaxf(nn, kEps);
    nx /= nd; ny /= nd; nz /= nd;
    float pn = sqrtf(px_ * px_ + py_ * py_ + pz_ * pz_);
    float pd = fmaxf(pn, kEps);
    float lx = -px_ / pd, ly = -py_ / pd, lz = -pz_ / pd;
    float s = nx * lx + ny * ly + nz * lz;
    float ndl = fmaxf(s, 0.0f);
    float rx = 2.0f * s * nx - lx;
    float ry = 2.0f * s * ny - ly;
    float rz = 2.0f * s * nz - lz;
    float vdr = fmaxf(lx * rx + ly * ry + lz * rz, 0.0f);
    float q = vdr;               // vdr^64 via 6 squarings
    q = q * q; q = q * q; q = q * q; q = q * q; q = q * q; q = q * q;
    float shade = 0.5f * (0.5f + 0.3f * ndl) + 0.2f * q;
    r = fminf(fmaxf(shade, 0.0f), 255.0f);
    a = 1.0f;
  } else {
    r = 1.0f;   // background rgb = 1.0
    a = 0.0f;   // mask = 0
  }
  float4* op = (float4*)out;
  op[((size_t)b * kH + y) * kW + x] = make_float4(r, r, r, a);
}

}  // namespace

extern "C" void kernel_launch(void* const* d_in, const int* in_sizes, int n_in,
                              void* d_out, int out_size, void* d_ws, size_t ws_size,
                              hipStream_t stream) {
  (void)in_sizes; (void)n_in; (void)out_size; (void)ws_size;
  const float* verts = (const float*)d_in[0];   // (B, NV, 3) f32
  const int* faces = (const int*)d_in[1];       // (NF, 3) i32
  float* out = (float*)d_out;                   // (B, H, W, 4) f32
  float* ws = (float*)d_ws;

  // ws layout (floats): [0, 30144) normal accum/normals; [30144, 70328) proj
  // float4s; [70328, ...) face data (B*NF*4 float4 = 1.22 MiB). Total ~1.5 MiB.
  float* nacc = ws;
  float4* proj = (float4*)(ws + 30144);
  float4* fd = (float4*)(ws + 70328);

  int nTot = kB * kNV * 3;
  hipLaunchKernelGGL(zero_k, dim3((nTot + 255) / 256), dim3(256), 0, stream,
                     nacc, nTot);
  hipLaunchKernelGGL(normal_accum_k, dim3((kB * kNF + 255) / 256), dim3(256), 0,
                     stream, verts, faces, nacc);
  hipLaunchKernelGGL(proj_norm_k, dim3((kB * kNV + 255) / 256), dim3(256), 0,
                     stream, verts, nacc, proj);
  hipLaunchKernelGGL(face_setup_k, dim3((kB * kNF + 255) / 256), dim3(256), 0,
                     stream, proj, faces, fd);
  hipLaunchKernelGGL(raster_k, dim3(32, 32, kB), dim3(256), 0, stream,
                     fd, verts, nacc, faces, out);
}

// Round 3
// 380.329 us; speedup vs baseline: 10.1300x; 5.5323x over previous
//
#include <hip/hip_runtime.h>
#include <math.h>

namespace {

constexpr int kH = 500, kW = 500, kNV = 5023, kNF = 9976, kB = 2;
constexpr float kFocal = 1015.0f;
constexpr float kEps = 1e-6f;
constexpr int kChunk = 256;        // faces examined per chunk
constexpr int kS = 8;              // face strips per batch (9976 % 8 == 0)
constexpr int kFPS = kNF / kS;     // 1247 faces per strip
constexpr unsigned long long kInitKey =
    (0x7F800000ull << 32) | 0xFFFFFFFFull;   // {z=+inf, idx=~0}

__global__ void init_k(float* nacc, unsigned long long* keys) {
  int i = blockIdx.x * 256 + threadIdx.x;
  if (i < kB * kNV * 3) nacc[i] = 0.0f;
  if (i < kB * kH * kW) keys[i] = kInitKey;
}

__device__ inline void cross3(float ax, float ay, float az,
                              float bx, float by, float bz,
                              float& cx, float& cy, float& cz) {
  cx = ay * bz - az * by;
  cy = az * bx - ax * bz;
  cz = ax * by - ay * bx;
}

// Scatter-add face cross products into per-vertex normal accumulator.
// Float-atomic order nondeterminism only perturbs continuous shading.
__global__ void normal_accum_k(const float* __restrict__ verts,
                               const int* __restrict__ faces,
                               float* __restrict__ nacc) {
  int idx = blockIdx.x * 256 + threadIdx.x;
  if (idx >= kB * kNF) return;
  int b = idx / kNF, f = idx - b * kNF;
  int i0 = faces[3 * f + 0], i1 = faces[3 * f + 1], i2 = faces[3 * f + 2];
  const float* vb = verts + (size_t)b * kNV * 3;
  float x0 = vb[3 * i0], y0 = vb[3 * i0 + 1], z0 = vb[3 * i0 + 2];
  float x1 = vb[3 * i1], y1 = vb[3 * i1 + 1], z1 = vb[3 * i1 + 2];
  float x2 = vb[3 * i2], y2 = vb[3 * i2 + 1], z2 = vb[3 * i2 + 2];
  float* nb = nacc + (size_t)b * kNV * 3;
  float cx, cy, cz;
  cross3(x2 - x1, y2 - y1, z2 - z1, x0 - x1, y0 - y1, z0 - z1, cx, cy, cz);
  atomicAdd(nb + 3 * i1 + 0, cx);
  atomicAdd(nb + 3 * i1 + 1, cy);
  atomicAdd(nb + 3 * i1 + 2, cz);
  cross3(x0 - x2, y0 - y2, z0 - z2, x1 - x2, y1 - y2, z1 - z2, cx, cy, cz);
  atomicAdd(nb + 3 * i2 + 0, cx);
  atomicAdd(nb + 3 * i2 + 1, cy);
  atomicAdd(nb + 3 * i2 + 2, cz);
  cross3(x1 - x0, y1 - y0, z1 - z0, x2 - x0, y2 - y0, z2 - z0, cx, cy, cz);
  atomicAdd(nb + 3 * i0 + 0, cx);
  atomicAdd(nb + 3 * i0 + 1, cy);
  atomicAdd(nb + 3 * i0 + 2, cz);
}

// Normalize normals in place; project vertices with the reference's exact
// fp32 rounding (_rn intrinsics block FMA contraction).
__global__ void proj_norm_k(const float* __restrict__ verts,
                            float* __restrict__ nacc,
                            float4* __restrict__ proj) {
  int idx = blockIdx.x * 256 + threadIdx.x;
  if (idx >= kB * kNV) return;
  float nx = nacc[3 * idx + 0], ny = nacc[3 * idx + 1], nz = nacc[3 * idx + 2];
  float nn = sqrtf(nx * nx + ny * ny + nz * nz);
  float nd = fmaxf(nn, kEps);
  nacc[3 * idx + 0] = nx / nd;
  nacc[3 * idx + 1] = ny / nd;
  nacc[3 * idx + 2] = nz / nd;
  float vx = verts[3 * idx + 0], vy = verts[3 * idx + 1], vz = verts[3 * idx + 2];
  float xc = -vx, yc = vy, zc = -vz;
  float zs = fmaxf(zc, kEps);
  float px = __fsub_rn(0.5f * kW, __fdiv_rn(__fmul_rn(kFocal, xc), zs));
  float py = __fsub_rn(0.5f * kH, __fdiv_rn(__fmul_rn(kFocal, yc), zs));
  proj[idx] = make_float4(px, py, zc, 0.0f);
}

// Exact per-face data (3 float4): {cx,cy,A0,B0} {A1,B1,den,za} {zb,zc,0,0}
// Prefilter data (4 float4): [0] bbox (inf sentinel if invalid)
//   [1] {P0,Q0,R0,mw}  [2] {P1,Q1,R1,mz}  [3] {dza,dzb,zc,·}
// where w0 ~ P0*x+Q0*y+R0 (affine barycentric), mw/mz are conservative
// per-face error bounds (8x headroom over the ~2^-21 evaluation error).
__global__ void face_setup_k(const float4* __restrict__ proj,
                             const int* __restrict__ faces,
                             float4* __restrict__ fdE,
                             float4* __restrict__ fdP) {
  int idx = blockIdx.x * 256 + threadIdx.x;
  if (idx >= kB * kNF) return;
  int b = idx / kNF, f = idx - b * kNF;
  int i0 = faces[3 * f + 0], i1 = faces[3 * f + 1], i2 = faces[3 * f + 2];
  float4 A = proj[b * kNV + i0];
  float4 Bv = proj[b * kNV + i1];
  float4 C = proj[b * kNV + i2];
  float ax = A.x, ay = A.y, za = A.z;
  float bx = Bv.x, by = Bv.y, zb = Bv.z;
  float cx = C.x, cy = C.y, zc = C.z;
  float A0 = __fsub_rn(by, cy);
  float B0 = __fsub_rn(cx, bx);
  float A1 = __fsub_rn(cy, ay);
  float B1 = __fsub_rn(ax, cx);
  float e = __fsub_rn(ay, cy);
  float den = __fadd_rn(__fmul_rn(A0, B1), __fmul_rn(B0, e));
  bool valid = (fabsf(den) >= kEps) && (za > kEps) && (zb > kEps) && (zc > kEps);
  float ds = valid ? den : 1.0f;

  float4* oe = fdE + (size_t)idx * 3;
  oe[0] = make_float4(cx, cy, A0, B0);
  oe[1] = make_float4(A1, B1, ds, za);
  oe[2] = make_float4(zb, zc, 0.0f, 0.0f);

  float P0 = A0 / ds, Q0 = B0 / ds, R0 = -(A0 * cx + B0 * cy) / ds;
  float P1 = A1 / ds, Q1 = B1 / ds, R1 = -(A1 * cx + B1 * cy) / ds;
  float dza = za - zc, dzb = zb - zc;
  float S0 = (fabsf(P0) + fabsf(Q0)) * 512.f + fabsf(R0);
  float S1 = (fabsf(P1) + fabsf(Q1)) * 512.f + fabsf(R1);
  float m0 = S0 * 0x1p-18f;
  float m1 = S1 * 0x1p-18f;
  float mw = m0 + m1 + 2e-6f;
  float mz = m0 * fabsf(dza) + m1 * fabsf(dzb) +
             0x1p-18f * (fabsf(zc) + fabsf(dza) + fabsf(dzb) + 1.f) + 2e-6f;

  float mnx, mxx, mny, mxy;
  if (valid) {
    mnx = fminf(fminf(ax, bx), cx) - 0.5f;
    mxx = fmaxf(fmaxf(ax, bx), cx) + 0.5f;
    mny = fminf(fminf(ay, by), cy) - 0.5f;
    mxy = fmaxf(fmaxf(ay, by), cy) + 0.5f;
  } else {
    mnx = INFINITY; mxx = -INFINITY; mny = INFINITY; mxy = -INFINITY;
  }
  float4* op = fdP + (size_t)idx * 4;
  op[0] = make_float4(mnx, mxx, mny, mxy);
  op[1] = make_float4(P0, Q0, R0, mw);
  op[2] = make_float4(P1, Q1, R1, mz);
  op[3] = make_float4(dza, dzb, zc, 0.0f);
}

// 16x16-pixel tile, one of kS face strips per block (grid.z = B*kS).
// Compaction: bbox-overlap AND edge-separation (triangle-vs-tile) cull.
// Pixel loop: 11-op affine prefilter with conservative per-face margins;
// only near-boundary / potential-winner candidates take the exact _rn path.
// Local lex-min (z,idx) merged globally via u64 atomicMin -> deterministic,
// identical to jnp.argmin first-min semantics.
__global__ __launch_bounds__(256) void raster_k(
    const float4* __restrict__ fdP, const float4* __restrict__ fdE,
    unsigned long long* __restrict__ keys) {
  __shared__ float4 sA[kChunk], sB[kChunk], sC[kChunk];
  __shared__ int lcnt;
  int bz = blockIdx.z;
  int b = bz >> 3, s = bz & 7;
  int fs = s * kFPS, fe = fs + kFPS;
  size_t bOff = (size_t)b * kNF;

  int tx = threadIdx.x & 15, ty = threadIdx.x >> 4;
  int x = blockIdx.x * 16 + tx;
  int y = blockIdx.y * 16 + ty;
  float xp = (float)x + 0.5f;
  float yp = (float)y + 0.5f;
  float tX0 = blockIdx.x * 16 + 0.5f, tX1 = blockIdx.x * 16 + 15.5f;
  float tY0 = blockIdx.y * 16 + 0.5f, tY1 = blockIdx.y * 16 + 15.5f;

  float zmin = INFINITY;
  int best = 0x7FFFFFFF;

  for (int base = fs; base < fe; base += kChunk) {
    __syncthreads();
    if (threadIdx.x == 0) lcnt = 0;
    __syncthreads();
    int j = base + threadIdx.x;
    if (j < fe) {
      float4 bb = fdP[(bOff + j) * 4 + 0];
      if (bb.x <= tX1 && bb.y >= tX0 && bb.z <= tY1 && bb.w >= tY0) {
        float4 r0 = fdP[(bOff + j) * 4 + 1];
        float4 r1 = fdP[(bOff + j) * 4 + 2];
        // Edge-separation: max/min of each affine w over the tile corners.
        float hi0 = fmaf(r0.x, r0.x >= 0.f ? tX1 : tX0,
                         fmaf(r0.y, r0.y >= 0.f ? tY1 : tY0, r0.z));
        float lo0 = fmaf(r0.x, r0.x >= 0.f ? tX0 : tX1,
                         fmaf(r0.y, r0.y >= 0.f ? tY0 : tY1, r0.z));
        float hi1 = fmaf(r1.x, r1.x >= 0.f ? tX1 : tX0,
                         fmaf(r1.y, r1.y >= 0.f ? tY1 : tY0, r1.z));
        float lo1 = fmaf(r1.x, r1.x >= 0.f ? tX0 : tX1,
                         fmaf(r1.y, r1.y >= 0.f ? tY0 : tY1, r1.z));
        float m2 = 2.f * r0.w;   // 2*mw: cull threshold looser than pixel test
        if (hi0 >= -m2 && hi1 >= -m2 && (1.f - lo0 - lo1) >= -m2) {
          int pos = atomicAdd(&lcnt, 1);
          float4 r2 = fdP[(bOff + j) * 4 + 3];
          r2.w = __int_as_float(j);
          sA[pos] = r0; sB[pos] = r1; sC[pos] = r2;
        }
      }
    }
    __syncthreads();
    int m = lcnt;
    for (int k = 0; k < m; ++k) {
      float4 a = sA[k];
      float4 bq = sB[k];
      float4 c = sC[k];
      float w0a = fmaf(a.x, xp, fmaf(a.y, yp, a.z));
      float w1a = fmaf(bq.x, xp, fmaf(bq.y, yp, bq.z));
      float w2a = 1.f - w0a - w1a;
      float zl = fmaf(w0a, c.x, fmaf(w1a, c.y, c.z));
      float wmin = fminf(fminf(w0a, w1a), w2a);
      if (wmin >= -a.w && zl <= zmin + bq.w) {
        // Exact path: replicate reference fp32 rounding bit-for-bit.
        int fi = __float_as_int(c.w);
        const float4* ep = fdE + (bOff + fi) * 3;
        float4 e0 = ep[0], e1 = ep[1], e2 = ep[2];
        float dx = __fsub_rn(xp, e0.x), dy = __fsub_rn(yp, e0.y);
        float num0 = __fadd_rn(__fmul_rn(e0.z, dx), __fmul_rn(e0.w, dy));
        float num1 = __fadd_rn(__fmul_rn(e1.x, dx), __fmul_rn(e1.y, dy));
        float w0 = __fdiv_rn(num0, e1.z);
        float w1 = __fdiv_rn(num1, e1.z);
        float w2 = __fsub_rn(__fsub_rn(1.f, w0), w1);
        if (w0 >= 0.f && w1 >= 0.f && w2 >= 0.f) {
          float z = __fadd_rn(
              __fadd_rn(__fmul_rn(w0, e1.w), __fmul_rn(w1, e2.x)),
              __fmul_rn(w2, e2.y));
          if (z < zmin || (z == zmin && fi < best)) { zmin = z; best = fi; }
        }
      }
    }
  }

  if (x < kW && y < kH && zmin < INFINITY) {
    unsigned long long key =
        ((unsigned long long)__float_as_uint(zmin) << 32) | (unsigned)best;
    atomicMin(keys + ((size_t)b * kH + y) * kW + x, key);
  }
}

// Per pixel: decode winner, recompute its exact barycentrics, shade.
__global__ void shade_k(const unsigned long long* __restrict__ keys,
                        const float4* __restrict__ fdE,
                        const float* __restrict__ verts,
                        const float* __restrict__ nrm,
                        const int* __restrict__ faces,
                        float* __restrict__ out) {
  int p = blockIdx.x * 256 + threadIdx.x;
  if (p >= kB * kH * kW) return;
  int b = p / (kH * kW);
  int r = p - b * kH * kW;
  int y = r / kW, x = r - y * kW;
  unsigned long long key = keys[p];
  float rv, av;
  if (key == kInitKey) {
    rv = 1.0f; av = 0.0f;
  } else {
    int fi = (int)(key & 0xFFFFFFFFull);
    float xp = (float)x + 0.5f, yp = (float)y + 0.5f;
    const float4* ep = fdE + ((size_t)b * kNF + fi) * 3;
    float4 e0 = ep[0], e1 = ep[1];
    float dx = __fsub_rn(xp, e0.x), dy = __fsub_rn(yp, e0.y);
    float num0 = __fadd_rn(__fmul_rn(e0.z, dx), __fmul_rn(e0.w, dy));
    float num1 = __fadd_rn(__fmul_rn(e1.x, dx), __fmul_rn(e1.y, dy));
    float w0 = __fdiv_rn(num0, e1.z);
    float w1 = __fdiv_rn(num1, e1.z);
    float w2 = __fsub_rn(__fsub_rn(1.f, w0), w1);
    int i0 = faces[3 * fi + 0], i1 = faces[3 * fi + 1], i2 = faces[3 * fi + 2];
    const float* vb = verts + (size_t)b * kNV * 3;
    const float* nb = nrm + (size_t)b * kNV * 3;
    float px_ = w0 * vb[3 * i0 + 0] + w1 * vb[3 * i1 + 0] + w2 * vb[3 * i2 + 0];
    float py_ = w0 * vb[3 * i0 + 1] + w1 * vb[3 * i1 + 1] + w2 * vb[3 * i2 + 1];
    float pz_ = w0 * vb[3 * i0 + 2] + w1 * vb[3 * i1 + 2] + w2 * vb[3 * i2 + 2];
    float nx = w0 * nb[3 * i0 + 0] + w1 * nb[3 * i1 + 0] + w2 * nb[3 * i2 + 0];
    float ny = w0 * nb[3 * i0 + 1] + w1 * nb[3 * i1 + 1] + w2 * nb[3 * i2 + 1];
    float nz = w0 * nb[3 * i0 + 2] + w1 * nb[3 * i1 + 2] + w2 * nb[3 * i2 + 2];
    float nn = sqrtf(nx * nx + ny * ny + nz * nz);
    float nd = fmaxf(nn, kEps);
    nx /= nd; ny /= nd; nz /= nd;
    float pn = sqrtf(px_ * px_ + py_ * py_ + pz_ * pz_);
    float pd = fmaxf(pn, kEps);
    float lx = -px_ / pd, ly = -py_ / pd, lz = -pz_ / pd;
    float sdot = nx * lx + ny * ly + nz * lz;
    float ndl = fmaxf(sdot, 0.0f);
    float rx = 2.0f * sdot * nx - lx;
    float ry = 2.0f * sdot * ny - ly;
    float rz = 2.0f * sdot * nz - lz;
    float vdr = fmaxf(lx * rx + ly * ry + lz * rz, 0.0f);
    float q = vdr;   // vdr^64 via 6 squarings
    q = q * q; q = q * q; q = q * q; q = q * q; q = q * q; q = q * q;
    float shade = 0.5f * (0.5f + 0.3f * ndl) + 0.2f * q;
    rv = fminf(fmaxf(shade, 0.0f), 255.0f);
    av = 1.0f;
  }
  ((float4*)out)[p] = make_float4(rv, rv, rv, av);
}

}  // namespace

extern "C" void kernel_launch(void* const* d_in, const int* in_sizes, int n_in,
                              void* d_out, int out_size, void* d_ws, size_t ws_size,
                              hipStream_t stream) {
  (void)in_sizes; (void)n_in; (void)out_size; (void)ws_size;
  const float* verts = (const float*)d_in[0];   // (B, NV, 3) f32
  const int* faces = (const int*)d_in[1];       // (NF, 3) i32
  float* out = (float*)d_out;                   // (B, H, W, 4) f32
  float* ws = (float*)d_ws;

  // ws layout (float offsets):
  //   nacc @ 0        (30,138 used)
  //   proj @ 30,720   (float4 x 10,046)
  //   fdE  @ 71,680   (float4 x 59,856)
  //   fdP  @ 311,296  (float4 x 79,808)
  //   keys @ 630,784  (u64 x 500,000)  -> total ~6.5 MiB
  float* nacc = ws;
  float4* proj = (float4*)(ws + 30720);
  float4* fdE = (float4*)(ws + 71680);
  float4* fdP = (float4*)(ws + 311296);
  unsigned long long* keys = (unsigned long long*)(ws + 630784);

  int nInit = kB * kH * kW;   // 500,000 >= kB*kNV*3
  hipLaunchKernelGGL(init_k, dim3((nInit + 255) / 256), dim3(256), 0, stream,
                     nacc, keys);
  hipLaunchKernelGGL(normal_accum_k, dim3((kB * kNF + 255) / 256), dim3(256), 0,
                     stream, verts, faces, nacc);
  hipLaunchKernelGGL(proj_norm_k, dim3((kB * kNV + 255) / 256), dim3(256), 0,
                     stream, verts, nacc, proj);
  hipLaunchKernelGGL(face_setup_k, dim3((kB * kNF + 255) / 256), dim3(256), 0,
                     stream, proj, faces, fdE, fdP);
  hipLaunchKernelGGL(raster_k, dim3(32, 32, kB * kS), dim3(256), 0, stream,
                     fdP, fdE, keys);
  hipLaunchKernelGGL(shade_k, dim3((kB * kH * kW + 255) / 256), dim3(256), 0,
                     stream, keys, fdE, verts, nacc, faces, out);
}